// Round 5
// baseline (110.426 us; speedup 1.0000x reference)
//
#include <hip/hip_runtime.h>
#include <stdint.h>

#define NV 16
#define NC 16
#define NH 1024
#define NW 1024
#define NRM 8
#define NRD 4

typedef __attribute__((ext_vector_type(4))) _Float16 f16x4;
typedef __attribute__((ext_vector_type(2))) __fp16 fp16x2_raw;
typedef __attribute__((ext_vector_type(4))) float f32x4;

#define MFMA16(a, b, c) __builtin_amdgcn_mfma_f32_16x16x16f16((a), (b), (c), 0, 0, 0)

__device__ __forceinline__ uint32_t pkh(float a, float b) {
    fp16x2_raw h = __builtin_amdgcn_cvt_pkrtz(a, b);   // lo = a, hi = b, RTZ
    return __builtin_bit_cast(uint32_t, h);
}

__device__ __forceinline__ f16x4 mk4(uint32_t lo, uint32_t hi) {
    union { uint32_t u[2]; f16x4 v; } t;
    t.u[0] = lo; t.u[1] = hi;
    return t.v;
}

// atan2 emitting REVOLUTIONS (atan2/2pi); poly = minimax deg-11 scaled by 1/2pi.
__device__ __forceinline__ float atan2_rev(float y, float x) {
    float ax = fabsf(x), ay = fabsf(y);
    float mx = fmaxf(ax, ay), mn = fminf(ax, ay);
    float a = mn * __builtin_amdgcn_rcpf(mx);
    float s = a * a;
    float p =              -0.00186549f;
    p = fmaf(p, s,  0.00838003f);
    p = fmaf(p, s, -0.01852970f);
    p = fmaf(p, s,  0.03080340f);
    p = fmaf(p, s, -0.05294381f);
    p = fmaf(p, s,  0.15915132f);
    p = p * a;
    float t = (ay > ax) ? (0.25f - p) : p;
    t = (x < 0.0f) ? (0.5f - t) : t;
    return (y < 0.0f) ? -t : t;
}

// exponent-domain constants for w=(wr,wi):
//  log2(m) = A*L2 - B*th ;  phase_rev = C*th + D*L2
//  A=0.5*wr  B=wi*2pi*log2e  C=wr  D=wi*ln2/(4pi)
#define K_B 9.06472028f
#define K_D 0.05516054f

#define CMAC(AR, AI, BR, BI) do { \
    tr_ = fmaf((AR), (BR), fmaf(-(AI), (BI), tr_)); \
    ti_ = fmaf((AR), (BI), fmaf( (AI), (BR), ti_)); } while (0)

// -------- pre-pass: transpose mod_v/del_v to [c][w][r] (contiguous r) --------
__global__ __launch_bounds__(256)
void transpose_v(const float* __restrict__ mod_v, const float* __restrict__ del_v,
                 float* __restrict__ mvT, float* __restrict__ dvT)
{
    const int idx = blockIdx.x * 256 + threadIdx.x;   // c*NW + w
    const int c = idx >> 10, w = idx & 1023;
    float2* mt = reinterpret_cast<float2*>(mvT) + idx * NRM;
    const float2* ms = reinterpret_cast<const float2*>(mod_v) + c * NRM * NW + w;
    #pragma unroll
    for (int r = 0; r < NRM; ++r) mt[r] = ms[r * NW];
    float2* dt = reinterpret_cast<float2*>(dvT) + idx * NRD;
    const float2* dsrc = reinterpret_cast<const float2*>(del_v) + c * NRD * NW + w;
    #pragma unroll
    for (int r = 0; r < NRD; ++r) dt[r] = dsrc[r * NW];
}

struct V6 { float4 m0, m1, m2, m3, d0, d1; };

template <bool TR>
__device__ __forceinline__ V6 load_v(const float* __restrict__ mvT, const float* __restrict__ dvT,
                                     const float* __restrict__ mod_v, const float* __restrict__ del_v,
                                     int c, int w)
{
    V6 r;
    if (TR) {
        const float4* mp = reinterpret_cast<const float4*>(mvT) + (c * NW + w) * 4;
        r.m0 = mp[0]; r.m1 = mp[1]; r.m2 = mp[2]; r.m3 = mp[3];
        const float4* dp = reinterpret_cast<const float4*>(dvT) + (c * NW + w) * 2;
        r.d0 = dp[0]; r.d1 = dp[1];
    } else {
        const float2* m = reinterpret_cast<const float2*>(mod_v) + c * NRM * NW + w;
        float2 a0 = m[0], a1 = m[NW], a2 = m[2*NW], a3 = m[3*NW];
        float2 a4 = m[4*NW], a5 = m[5*NW], a6 = m[6*NW], a7 = m[7*NW];
        r.m0 = make_float4(a0.x, a0.y, a1.x, a1.y);
        r.m1 = make_float4(a2.x, a2.y, a3.x, a3.y);
        r.m2 = make_float4(a4.x, a4.y, a5.x, a5.y);
        r.m3 = make_float4(a6.x, a6.y, a7.x, a7.y);
        const float2* d = reinterpret_cast<const float2*>(del_v) + c * NRD * NW + w;
        float2 b0 = d[0], b1 = d[NW], b2 = d[2*NW], b3 = d[3*NW];
        r.d0 = make_float4(b0.x, b0.y, b1.x, b1.y);
        r.d1 = make_float4(b2.x, b2.y, b3.x, b3.y);
    }
    return r;
}

template <bool TR>
__global__ __launch_bounds__(256)
void fused_kernel(const float* __restrict__ base, const float* __restrict__ mod_u,
                  const float* __restrict__ mod_v, const float* __restrict__ del_u,
                  const float* __restrict__ del_v, const float* __restrict__ exp_base,
                  const float* __restrict__ exp_mod, const float* __restrict__ exp_del,
                  const float* __restrict__ bias_, const float* __restrict__ scale_,
                  const float* __restrict__ coef, float* __restrict__ out,
                  const float* __restrict__ mvT, const float* __restrict__ dvT)
{
    // wave-private staging: [2 rows][4 waves][64 pixels][16 c] u32 (f16 r,i packed)
    __shared__ uint32_t lds[8192];                 // 32 KB
    __shared__ float4 uA4[NC][2][4];               // mod_u rows, 2 KB
    __shared__ float4 uD4[NC][2][2];               // del_u rows, 1 KB
    __shared__ float4 ctab[NC][2];                 // (A,B,C,D) mod/del, 512 B

    const int tid    = threadIdx.x;
    const int lane   = tid & 63;
    const int wv     = tid >> 6;
    const int wchunk = (int)(blockIdx.x & 3);
    const int hp     = (int)(blockIdx.x >> 2);
    const int w      = (wchunk << 8) | tid;
    const int h0     = hp * 2;
    const int wbase  = (wchunk << 8) | (wv << 6);

    // ---------- cooperative preload of block-uniform tables ----------
    {
        float* uAf = reinterpret_cast<float*>(uA4);   // [c][rr][16 floats]
        float* uDf = reinterpret_cast<float*>(uD4);   // [c][rr][8 floats]
        int i = tid;
        {
            const int c = i >> 5, rr = (i >> 4) & 1, e = i & 15;
            uAf[i] = mod_u[((c * NH) + (h0 + rr)) * (NRM * 2) + e];
        }
        i = tid + 256;
        {
            const int c = i >> 5, rr = (i >> 4) & 1, e = i & 15;
            uAf[i] = mod_u[((c * NH) + (h0 + rr)) * (NRM * 2) + e];
        }
        if (tid < 256) {
            const int c = tid >> 4, rr = (tid >> 3) & 1, e = tid & 7;
            uDf[tid] = del_u[((c * NH) + (h0 + rr)) * (NRD * 2) + e];
        }
        if (tid < 32) {
            const int c = tid >> 1, which = tid & 1;
            const float* ep = which ? exp_del : exp_mod;
            const float wr = ep[2*c], wi = ep[2*c+1];
            ctab[c][which] = make_float4(0.5f * wr, wi * K_B, wr, wi * K_D);
        }
    }
    __syncthreads();

    // ---------- per-thread A-fragments + bias-const accumulator seed ----------
    const int vv = lane & 15;          // M index (v)
    const int c0 = (lane >> 4) << 2;   // K block (c)

    const float4 cfa = *reinterpret_cast<const float4*>(coef   + (vv * NC + c0) * 2);
    const float4 cfb = *reinterpret_cast<const float4*>(coef   + (vv * NC + c0) * 2 + 4);
    const float4 sca = *reinterpret_cast<const float4*>(scale_ + c0 * 2);
    const float4 scb = *reinterpret_cast<const float4*>(scale_ + c0 * 2 + 4);
    const float4 bia = *reinterpret_cast<const float4*>(bias_  + c0 * 2);
    const float4 bib = *reinterpret_cast<const float4*>(bias_  + c0 * 2 + 4);

    float c2r0 = cfa.x*sca.x - cfa.y*sca.y, c2i0 = cfa.x*sca.y + cfa.y*sca.x;
    float c2r1 = cfa.z*sca.z - cfa.w*sca.w, c2i1 = cfa.z*sca.w + cfa.w*sca.z;
    float c2r2 = cfb.x*scb.x - cfb.y*scb.y, c2i2 = cfb.x*scb.y + cfb.y*scb.x;
    float c2r3 = cfb.z*scb.z - cfb.w*scb.w, c2i3 = cfb.z*scb.w + cfb.w*scb.z;

    const f16x4 Ar = mk4(pkh(c2r0, c2r1), pkh(c2r2, c2r3));
    const f16x4 Ai = mk4(pkh(c2i0, c2i1), pkh(c2i2, c2i3));
    const f16x4 An = mk4(pkh(-c2i0, -c2i1), pkh(-c2i2, -c2i3));

    const f16x4 Kr = mk4(pkh(cfa.x, cfa.z), pkh(cfb.x, cfb.z));
    const f16x4 Ki = mk4(pkh(cfa.y, cfa.w), pkh(cfb.y, cfb.w));
    const f16x4 Kn = mk4(pkh(-cfa.y, -cfa.w), pkh(-cfb.y, -cfb.w));

    const f16x4 Bbr = mk4(pkh(bia.x, bia.z), pkh(bib.x, bib.z));
    const f16x4 Bbi = mk4(pkh(bia.y, bia.w), pkh(bib.y, bib.w));

    const f32x4 zero4 = {0.f, 0.f, 0.f, 0.f};
    const f32x4 cr4 = MFMA16(Kr, Bbr, MFMA16(Kn, Bbi, zero4));  // Re(sum coef*bias)
    const f32x4 ci4 = MFMA16(Ki, Bbr, MFMA16(Kr, Bbi, zero4));  // Im(sum coef*bias)

    // ---------- base contribution in exponent domain, per row ----------
    const float ebr = exp_base[0], ebi = exp_base[1];
    const float Ab = 0.5f * ebr, Bb = ebi * K_B, Cb = ebr, Db = ebi * K_D;
    float berr[2], beir[2];
    {
        const float2 b0 = reinterpret_cast<const float2*>(base)[(h0    ) * NW + w];
        const float2 b1 = reinterpret_cast<const float2*>(base)[(h0 + 1) * NW + w];
        const float L2b0 = __builtin_amdgcn_logf(fmaf(b0.x, b0.x, b0.y * b0.y));
        const float th0  = atan2_rev(b0.y, b0.x);
        const float L2b1 = __builtin_amdgcn_logf(fmaf(b1.x, b1.x, b1.y * b1.y));
        const float th1  = atan2_rev(b1.y, b1.x);
        berr[0] = fmaf(Ab, L2b0, -Bb * th0);
        beir[0] = fmaf(Cb, th0,   Db * L2b0);
        berr[1] = fmaf(Ab, L2b1, -Bb * th1);
        beir[1] = fmaf(Cb, th1,   Db * L2b1);
    }

    uint32_t* wlds0 = lds + (wv << 10);          // row 0 region (4 KB/wave)
    uint32_t* wlds1 = lds + 4096 + (wv << 10);   // row 1 region
    const int swz_w = (lane >> 1) & 3;

    // ---------- main loop over c with register prefetch ----------
    V6 cur = load_v<TR>(mvT, dvT, mod_v, del_v, 0, w);

    #pragma unroll 1
    for (int a = 0; a < 4; ++a) {
        uint32_t p0[4], p1[4];
        #pragma unroll
        for (int j = 0; j < 4; ++j) {
            const int c = (a << 2) | j;
            V6 nxt = load_v<TR>(mvT, dvT, mod_v, del_v, (c + 1) & 15, w);

            const float4 km = ctab[c][0];   // (A,B,C,D) for mod
            const float4 kd = ctab[c][1];   // (A,B,C,D) for del

            #pragma unroll
            for (int rr = 0; rr < 2; ++rr) {
                const float4 ua  = uA4[c][rr][0];
                const float4 ub  = uA4[c][rr][1];
                const float4 uc_ = uA4[c][rr][2];
                const float4 ud  = uA4[c][rr][3];
                const float4 da  = uD4[c][rr][0];
                const float4 db  = uD4[c][rr][1];

                float tr_ = 0.f, ti_ = 0.f;
                CMAC(ua.x,  ua.y,  cur.m0.x, cur.m0.y);
                CMAC(ua.z,  ua.w,  cur.m0.z, cur.m0.w);
                CMAC(ub.x,  ub.y,  cur.m1.x, cur.m1.y);
                CMAC(ub.z,  ub.w,  cur.m1.z, cur.m1.w);
                CMAC(uc_.x, uc_.y, cur.m2.x, cur.m2.y);
                CMAC(uc_.z, uc_.w, cur.m2.z, cur.m2.w);
                CMAC(ud.x,  ud.y,  cur.m3.x, cur.m3.y);
                CMAC(ud.z,  ud.w,  cur.m3.z, cur.m3.w);
                const float mr = tr_, mi_ = ti_;

                tr_ = 0.f; ti_ = 0.f;
                CMAC(da.x, da.y, cur.d0.x, cur.d0.y);
                CMAC(da.z, da.w, cur.d0.z, cur.d0.w);
                CMAC(db.x, db.y, cur.d1.x, cur.d1.y);
                CMAC(db.z, db.w, cur.d1.z, cur.d1.w);
                const float dr = tr_, di = ti_;

                // mod power, base-folded: pb*pm = exp2(er2)·cis(2pi·eir)
                const float L2m = __builtin_amdgcn_logf(fmaf(mr, mr, mi_ * mi_));
                const float thm = atan2_rev(mi_, mr);
                const float er2 = fmaf(km.x, L2m, fmaf(-km.y, thm, berr[rr]));
                const float eir = fmaf(km.z, thm, fmaf(km.w, L2m, beir[rr]));
                const float mm  = __builtin_amdgcn_exp2f(er2);
                const float fm  = __builtin_amdgcn_fractf(eir);
                const float cv  = __builtin_amdgcn_cosf(fm);
                const float sv  = __builtin_amdgcn_sinf(fm);

                // del power
                const float L2d = __builtin_amdgcn_logf(fmaf(dr, dr, di * di));
                const float thd = atan2_rev(di, dr);
                const float er2d = fmaf(kd.x, L2d, -kd.y * thd);
                const float eird = fmaf(kd.z, thd,  kd.w * L2d);
                const float md  = __builtin_amdgcn_exp2f(er2d);
                const float fd  = __builtin_amdgcn_fractf(eird);
                const float cvd = __builtin_amdgcn_cosf(fd);
                const float svd = __builtin_amdgcn_sinf(fd);

                // P = pb*pm + pd
                const float Pr = fmaf(mm, cv, md * cvd);
                const float Pi = fmaf(mm, sv, md * svd);
                const uint32_t pk = pkh(Pr, Pi);
                if (rr == 0) p0[j] = pk; else p1[j] = pk;
            }
            cur = nxt;
        }
        const int s = (a ^ swz_w) << 2;   // swizzled 16B slot
        *reinterpret_cast<uint4*>(wlds0 + (lane << 4) + s) = make_uint4(p0[0], p0[1], p0[2], p0[3]);
        *reinterpret_cast<uint4*>(wlds1 + (lane << 4) + s) = make_uint4(p1[0], p1[1], p1[2], p1[3]);
    }

    // ---------- MFMA einsum: out[v,pix] = sum_c coef2[v,c] * P[c,pix] + const ----------
    const int ar  = lane >> 4;
    const int col = lane & 15;
    float2* outp = reinterpret_cast<float2*>(out);

    #pragma unroll
    for (int rr = 0; rr < 2; ++rr) {
        const uint32_t* reg = rr ? wlds1 : wlds0;
        const int h = h0 + rr;
        #pragma unroll
        for (int g = 0; g < 4; ++g) {
            const int p = (g << 4) | col;
            const int s = (ar ^ ((p >> 1) & 3)) << 2;
            const uint4 q = *reinterpret_cast<const uint4*>(reg + (p << 4) + s);
            const f16x4 Brf = mk4(__builtin_amdgcn_perm(q.y, q.x, 0x05040100u),
                                  __builtin_amdgcn_perm(q.w, q.z, 0x05040100u));
            const f16x4 Bif = mk4(__builtin_amdgcn_perm(q.y, q.x, 0x07060302u),
                                  __builtin_amdgcn_perm(q.w, q.z, 0x07060302u));
            const f32x4 Dr = MFMA16(Ar, Brf, MFMA16(An, Bif, cr4));
            const f32x4 Di = MFMA16(Ai, Brf, MFMA16(Ar, Bif, ci4));
            const int wg = wbase + (g << 4) + col;
            const int base_idx = h * NW + wg;
            #pragma unroll
            for (int j = 0; j < 4; ++j) {
                const int v = (ar << 2) + j;
                outp[v * (NH * NW) + base_idx] = make_float2(Dr[j], Di[j]);
            }
        }
    }
}

extern "C" void kernel_launch(void* const* d_in, const int* in_sizes, int n_in,
                              void* d_out, int out_size, void* d_ws, size_t ws_size,
                              hipStream_t stream) {
    const float* base     = (const float*)d_in[0];
    const float* mod_u    = (const float*)d_in[1];
    const float* mod_v    = (const float*)d_in[2];
    const float* del_u    = (const float*)d_in[3];
    const float* del_v    = (const float*)d_in[4];
    const float* exp_base = (const float*)d_in[5];
    const float* exp_mod  = (const float*)d_in[6];
    const float* exp_del  = (const float*)d_in[7];
    const float* bias_    = (const float*)d_in[8];
    const float* scale_   = (const float*)d_in[9];
    const float* coef     = (const float*)d_in[10];
    float* outp = (float*)d_out;

    const int blocks = (NH / 2) * (NW / 256);   // 2048
    const size_t mvT_floats = (size_t)NC * NW * NRM * 2;   // 1 MB
    const size_t dvT_floats = (size_t)NC * NW * NRD * 2;   // 0.5 MB
    const size_t need = (mvT_floats + dvT_floats) * sizeof(float);

    if (ws_size >= need) {
        float* mvT = (float*)d_ws;
        float* dvT = mvT + mvT_floats;
        transpose_v<<<(NC * NW) / 256, 256, 0, stream>>>(mod_v, del_v, mvT, dvT);
        fused_kernel<true><<<blocks, 256, 0, stream>>>(base, mod_u, mod_v, del_u, del_v,
                                                       exp_base, exp_mod, exp_del,
                                                       bias_, scale_, coef, outp, mvT, dvT);
    } else {
        fused_kernel<false><<<blocks, 256, 0, stream>>>(base, mod_u, mod_v, del_u, del_v,
                                                        exp_base, exp_mod, exp_del,
                                                        bias_, scale_, coef, outp,
                                                        (const float*)nullptr, (const float*)nullptr);
    }
}

// Round 6
// 99.165 us; speedup vs baseline: 1.1136x; 1.1136x over previous
//
#include <hip/hip_runtime.h>
#include <stdint.h>

#define NV 16
#define NC 16
#define NH 1024
#define NW 1024
#define NRM 8
#define NRD 4

typedef __attribute__((ext_vector_type(4))) _Float16 f16x4;
typedef __attribute__((ext_vector_type(2))) __fp16 fp16x2_raw;
typedef __attribute__((ext_vector_type(4))) float f32x4;
typedef __attribute__((ext_vector_type(2))) float f32x2;

#define MFMA16(a, b, c) __builtin_amdgcn_mfma_f32_16x16x16f16((a), (b), (c), 0, 0, 0)

__device__ __forceinline__ uint32_t pkh(float a, float b) {
    fp16x2_raw h = __builtin_amdgcn_cvt_pkrtz(a, b);   // lo = a, hi = b, RTZ
    return __builtin_bit_cast(uint32_t, h);
}

__device__ __forceinline__ f16x4 mk4(uint32_t lo, uint32_t hi) {
    union { uint32_t u[2]; f16x4 v; } t;
    t.u[0] = lo; t.u[1] = hi;
    return t.v;
}

// packed complex MAC: t(=tr,ti) += (a.x,a.y)*(b.x,b.y) complex, via 2x v_pk_fma_f32
// inst1: tr += ar*br ; ti += ar*bi      (src0 broadcast-lo)
// inst2: tr += -ai*bi ; ti += ai*br     (src0 broadcast-hi with neg_lo, src1 swapped)
__device__ __forceinline__ void cmac_pk(f32x2& t, f32x2 a, f32x2 b) {
    asm("v_pk_fma_f32 %0, %1, %2, %0 op_sel_hi:[0,1,1]"
        : "+v"(t) : "v"(a), "v"(b));
    asm("v_pk_fma_f32 %0, %1, %2, %0 op_sel:[1,1,0] op_sel_hi:[1,0,1] neg_lo:[1,0,0]"
        : "+v"(t) : "v"(a), "v"(b));
}

struct c2 { f32x2 a, b; };
__device__ __forceinline__ c2 split4(float4 v) {
    c2 r; r.a = f32x2{v.x, v.y}; r.b = f32x2{v.z, v.w}; return r;
}

// atan2 emitting REVOLUTIONS (atan2/2pi); poly = minimax deg-11 scaled by 1/2pi.
__device__ __forceinline__ float atan2_rev(float y, float x) {
    float ax = fabsf(x), ay = fabsf(y);
    float mx = fmaxf(ax, ay), mn = fminf(ax, ay);
    float a = mn * __builtin_amdgcn_rcpf(mx);
    float s = a * a;
    float p =              -0.00186549f;
    p = fmaf(p, s,  0.00838003f);
    p = fmaf(p, s, -0.01852970f);
    p = fmaf(p, s,  0.03080340f);
    p = fmaf(p, s, -0.05294381f);
    p = fmaf(p, s,  0.15915132f);
    p = p * a;
    float t = (ay > ax) ? (0.25f - p) : p;
    t = (x < 0.0f) ? (0.5f - t) : t;
    return (y < 0.0f) ? -t : t;
}

// exponent-domain constants for w=(wr,wi):
//  log2(m) = A*L2 - B*th ;  phase_rev = C*th + D*L2
//  A=0.5*wr  B=wi*2pi*log2e  C=wr  D=wi*ln2/(4pi)
#define K_B 9.06472028f
#define K_D 0.05516054f

// -------- pre-pass: transpose mod_v/del_v to [c][w][r] (contiguous r) --------
__global__ __launch_bounds__(256)
void transpose_v(const float* __restrict__ mod_v, const float* __restrict__ del_v,
                 float* __restrict__ mvT, float* __restrict__ dvT)
{
    const int idx = blockIdx.x * 256 + threadIdx.x;   // c*NW + w
    const int c = idx >> 10, w = idx & 1023;
    float2* mt = reinterpret_cast<float2*>(mvT) + idx * NRM;
    const float2* ms = reinterpret_cast<const float2*>(mod_v) + c * NRM * NW + w;
    #pragma unroll
    for (int r = 0; r < NRM; ++r) mt[r] = ms[r * NW];
    float2* dt = reinterpret_cast<float2*>(dvT) + idx * NRD;
    const float2* dsrc = reinterpret_cast<const float2*>(del_v) + c * NRD * NW + w;
    #pragma unroll
    for (int r = 0; r < NRD; ++r) dt[r] = dsrc[r * NW];
}

struct V6 { f32x2 m0, m1, m2, m3, m4, m5, m6, m7, d0, d1, d2, d3; };

template <bool TR>
__device__ __forceinline__ V6 load_v(const float* __restrict__ mvT, const float* __restrict__ dvT,
                                     const float* __restrict__ mod_v, const float* __restrict__ del_v,
                                     int c, int w)
{
    V6 r;
    if (TR) {
        const float4* mp = reinterpret_cast<const float4*>(mvT) + (c * NW + w) * 4;
        c2 q0 = split4(mp[0]), q1 = split4(mp[1]), q2 = split4(mp[2]), q3 = split4(mp[3]);
        r.m0 = q0.a; r.m1 = q0.b; r.m2 = q1.a; r.m3 = q1.b;
        r.m4 = q2.a; r.m5 = q2.b; r.m6 = q3.a; r.m7 = q3.b;
        const float4* dp = reinterpret_cast<const float4*>(dvT) + (c * NW + w) * 2;
        c2 s0 = split4(dp[0]), s1 = split4(dp[1]);
        r.d0 = s0.a; r.d1 = s0.b; r.d2 = s1.a; r.d3 = s1.b;
    } else {
        const float2* m = reinterpret_cast<const float2*>(mod_v) + c * NRM * NW + w;
        float2 a0 = m[0], a1 = m[NW], a2 = m[2*NW], a3 = m[3*NW];
        float2 a4 = m[4*NW], a5 = m[5*NW], a6 = m[6*NW], a7 = m[7*NW];
        r.m0 = f32x2{a0.x, a0.y}; r.m1 = f32x2{a1.x, a1.y};
        r.m2 = f32x2{a2.x, a2.y}; r.m3 = f32x2{a3.x, a3.y};
        r.m4 = f32x2{a4.x, a4.y}; r.m5 = f32x2{a5.x, a5.y};
        r.m6 = f32x2{a6.x, a6.y}; r.m7 = f32x2{a7.x, a7.y};
        const float2* d = reinterpret_cast<const float2*>(del_v) + c * NRD * NW + w;
        float2 b0 = d[0], b1 = d[NW], b2 = d[2*NW], b3 = d[3*NW];
        r.d0 = f32x2{b0.x, b0.y}; r.d1 = f32x2{b1.x, b1.y};
        r.d2 = f32x2{b2.x, b2.y}; r.d3 = f32x2{b3.x, b3.y};
    }
    return r;
}

template <bool TR>
__global__ __launch_bounds__(256)
void fused_kernel(const float* __restrict__ base, const float* __restrict__ mod_u,
                  const float* __restrict__ mod_v, const float* __restrict__ del_u,
                  const float* __restrict__ del_v, const float* __restrict__ exp_base,
                  const float* __restrict__ exp_mod, const float* __restrict__ exp_del,
                  const float* __restrict__ bias_, const float* __restrict__ scale_,
                  const float* __restrict__ coef, float* __restrict__ out,
                  const float* __restrict__ mvT, const float* __restrict__ dvT)
{
    // wave-private staging: [2 rows][4 waves][64 pixels][16 c] u32 (f16 r,i packed)
    __shared__ uint32_t lds[8192];                 // 32 KB
    __shared__ float4 uA4[NC][2][4];               // mod_u rows, 2 KB
    __shared__ float4 uD4[NC][2][2];               // del_u rows, 1 KB

    const int tid    = threadIdx.x;
    const int lane   = tid & 63;
    const int wv     = tid >> 6;
    const int wchunk = (int)(blockIdx.x & 3);
    const int hp     = (int)(blockIdx.x >> 2);
    const int w      = (wchunk << 8) | tid;
    const int h0     = hp * 2;
    const int wbase  = (wchunk << 8) | (wv << 6);

    // ---------- cooperative preload of block-uniform u-tables ----------
    {
        float* uAf = reinterpret_cast<float*>(uA4);   // [c][rr][16 floats]
        float* uDf = reinterpret_cast<float*>(uD4);   // [c][rr][8 floats]
        int i = tid;
        {
            const int c = i >> 5, rr = (i >> 4) & 1, e = i & 15;
            uAf[i] = mod_u[((c * NH) + (h0 + rr)) * (NRM * 2) + e];
        }
        i = tid + 256;
        {
            const int c = i >> 5, rr = (i >> 4) & 1, e = i & 15;
            uAf[i] = mod_u[((c * NH) + (h0 + rr)) * (NRM * 2) + e];
        }
        if (tid < 256) {
            const int c = tid >> 4, rr = (tid >> 3) & 1, e = tid & 7;
            uDf[tid] = del_u[((c * NH) + (h0 + rr)) * (NRD * 2) + e];
        }
    }
    __syncthreads();

    // ---------- per-thread A-fragments + bias-const accumulator seed ----------
    const int vv = lane & 15;          // M index (v)
    const int c0 = (lane >> 4) << 2;   // K block (c)

    const float4 cfa = *reinterpret_cast<const float4*>(coef   + (vv * NC + c0) * 2);
    const float4 cfb = *reinterpret_cast<const float4*>(coef   + (vv * NC + c0) * 2 + 4);
    const float4 sca = *reinterpret_cast<const float4*>(scale_ + c0 * 2);
    const float4 scb = *reinterpret_cast<const float4*>(scale_ + c0 * 2 + 4);
    const float4 bia = *reinterpret_cast<const float4*>(bias_  + c0 * 2);
    const float4 bib = *reinterpret_cast<const float4*>(bias_  + c0 * 2 + 4);

    float c2r0 = cfa.x*sca.x - cfa.y*sca.y, c2i0 = cfa.x*sca.y + cfa.y*sca.x;
    float c2r1 = cfa.z*sca.z - cfa.w*sca.w, c2i1 = cfa.z*sca.w + cfa.w*sca.z;
    float c2r2 = cfb.x*scb.x - cfb.y*scb.y, c2i2 = cfb.x*scb.y + cfb.y*scb.x;
    float c2r3 = cfb.z*scb.z - cfb.w*scb.w, c2i3 = cfb.z*scb.w + cfb.w*scb.z;

    const f16x4 Ar = mk4(pkh(c2r0, c2r1), pkh(c2r2, c2r3));
    const f16x4 Ai = mk4(pkh(c2i0, c2i1), pkh(c2i2, c2i3));
    const f16x4 An = mk4(pkh(-c2i0, -c2i1), pkh(-c2i2, -c2i3));

    const f16x4 Kr = mk4(pkh(cfa.x, cfa.z), pkh(cfb.x, cfb.z));
    const f16x4 Ki = mk4(pkh(cfa.y, cfa.w), pkh(cfb.y, cfb.w));
    const f16x4 Kn = mk4(pkh(-cfa.y, -cfa.w), pkh(-cfb.y, -cfb.w));

    const f16x4 Bbr = mk4(pkh(bia.x, bia.z), pkh(bib.x, bib.z));
    const f16x4 Bbi = mk4(pkh(bia.y, bia.w), pkh(bib.y, bib.w));

    const f32x4 zero4 = {0.f, 0.f, 0.f, 0.f};
    const f32x4 cr4 = MFMA16(Kr, Bbr, MFMA16(Kn, Bbi, zero4));  // Re(sum coef*bias)
    const f32x4 ci4 = MFMA16(Ki, Bbr, MFMA16(Kr, Bbi, zero4));  // Im(sum coef*bias)

    // ---------- base contribution in exponent domain, per row ----------
    const float ebr = exp_base[0], ebi = exp_base[1];
    const float Ab = 0.5f * ebr, Bb = ebi * K_B, Cb = ebr, Db = ebi * K_D;
    float berr[2], beir[2];
    {
        const float2 b0 = reinterpret_cast<const float2*>(base)[(h0    ) * NW + w];
        const float2 b1 = reinterpret_cast<const float2*>(base)[(h0 + 1) * NW + w];
        const float L2b0 = __builtin_amdgcn_logf(fmaf(b0.x, b0.x, b0.y * b0.y));
        const float th0  = atan2_rev(b0.y, b0.x);
        const float L2b1 = __builtin_amdgcn_logf(fmaf(b1.x, b1.x, b1.y * b1.y));
        const float th1  = atan2_rev(b1.y, b1.x);
        berr[0] = fmaf(Ab, L2b0, -Bb * th0);
        beir[0] = fmaf(Cb, th0,   Db * L2b0);
        berr[1] = fmaf(Ab, L2b1, -Bb * th1);
        beir[1] = fmaf(Cb, th1,   Db * L2b1);
    }

    uint32_t* wlds0 = lds + (wv << 10);          // row 0 region (4 KB/wave)
    uint32_t* wlds1 = lds + 4096 + (wv << 10);   // row 1 region
    const int swz_w = (lane >> 1) & 3;

    // ---------- main loop over c with register prefetch ----------
    V6 cur = load_v<TR>(mvT, dvT, mod_v, del_v, 0, w);

    #pragma unroll 1
    for (int a = 0; a < 4; ++a) {
        uint32_t p0[4], p1[4];
        #pragma unroll
        for (int j = 0; j < 4; ++j) {
            const int c = (a << 2) | j;
            V6 nxt = load_v<TR>(mvT, dvT, mod_v, del_v, (c + 1) & 15, w);

            // per-c exponent constants: uniform global loads (s_load-able), as in R4
            const float2 em = reinterpret_cast<const float2*>(exp_mod)[c];
            const float2 ed = reinterpret_cast<const float2*>(exp_del)[c];
            const float kmA = 0.5f * em.x, kmB = em.y * K_B, kmC = em.x, kmD = em.y * K_D;
            const float kdA = 0.5f * ed.x, kdB = ed.y * K_B, kdC = ed.x, kdD = ed.y * K_D;

            #pragma unroll
            for (int rr = 0; rr < 2; ++rr) {
                const c2 ua = split4(uA4[c][rr][0]);
                const c2 ub = split4(uA4[c][rr][1]);
                const c2 uc_ = split4(uA4[c][rr][2]);
                const c2 ud = split4(uA4[c][rr][3]);
                const c2 da = split4(uD4[c][rr][0]);
                const c2 db = split4(uD4[c][rr][1]);

                f32x2 tm = {0.f, 0.f};
                cmac_pk(tm, ua.a,  cur.m0); cmac_pk(tm, ua.b,  cur.m1);
                cmac_pk(tm, ub.a,  cur.m2); cmac_pk(tm, ub.b,  cur.m3);
                cmac_pk(tm, uc_.a, cur.m4); cmac_pk(tm, uc_.b, cur.m5);
                cmac_pk(tm, ud.a,  cur.m6); cmac_pk(tm, ud.b,  cur.m7);
                const float mr = tm[0], mi_ = tm[1];

                f32x2 td = {0.f, 0.f};
                cmac_pk(td, da.a, cur.d0); cmac_pk(td, da.b, cur.d1);
                cmac_pk(td, db.a, cur.d2); cmac_pk(td, db.b, cur.d3);
                const float dr = td[0], di = td[1];

                // mod power, base-folded: pb*pm = exp2(er2)·cis(2pi·eir)
                const float L2m = __builtin_amdgcn_logf(fmaf(mr, mr, mi_ * mi_));
                const float thm = atan2_rev(mi_, mr);
                const float er2 = fmaf(kmA, L2m, fmaf(-kmB, thm, berr[rr]));
                const float eir = fmaf(kmC, thm, fmaf(kmD, L2m, beir[rr]));
                const float mm  = __builtin_amdgcn_exp2f(er2);
                const float fm  = __builtin_amdgcn_fractf(eir);
                const float cv  = __builtin_amdgcn_cosf(fm);
                const float sv  = __builtin_amdgcn_sinf(fm);

                // del power
                const float L2d = __builtin_amdgcn_logf(fmaf(dr, dr, di * di));
                const float thd = atan2_rev(di, dr);
                const float er2d = fmaf(kdA, L2d, -kdB * thd);
                const float eird = fmaf(kdC, thd,  kdD * L2d);
                const float md  = __builtin_amdgcn_exp2f(er2d);
                const float fd  = __builtin_amdgcn_fractf(eird);
                const float cvd = __builtin_amdgcn_cosf(fd);
                const float svd = __builtin_amdgcn_sinf(fd);

                // P = pb*pm + pd
                const float Pr = fmaf(mm, cv, md * cvd);
                const float Pi = fmaf(mm, sv, md * svd);
                const uint32_t pk = pkh(Pr, Pi);
                if (rr == 0) p0[j] = pk; else p1[j] = pk;
            }
            cur = nxt;
        }
        const int s = (a ^ swz_w) << 2;   // swizzled 16B slot
        *reinterpret_cast<uint4*>(wlds0 + (lane << 4) + s) = make_uint4(p0[0], p0[1], p0[2], p0[3]);
        *reinterpret_cast<uint4*>(wlds1 + (lane << 4) + s) = make_uint4(p1[0], p1[1], p1[2], p1[3]);
    }

    // ---------- MFMA einsum: out[v,pix] = sum_c coef2[v,c] * P[c,pix] + const ----------
    const int ar  = lane >> 4;
    const int col = lane & 15;
    float2* outp = reinterpret_cast<float2*>(out);

    #pragma unroll
    for (int rr = 0; rr < 2; ++rr) {
        const uint32_t* reg = rr ? wlds1 : wlds0;
        const int h = h0 + rr;
        #pragma unroll
        for (int g = 0; g < 4; ++g) {
            const int p = (g << 4) | col;
            const int s = (ar ^ ((p >> 1) & 3)) << 2;
            const uint4 q = *reinterpret_cast<const uint4*>(reg + (p << 4) + s);
            const f16x4 Brf = mk4(__builtin_amdgcn_perm(q.y, q.x, 0x05040100u),
                                  __builtin_amdgcn_perm(q.w, q.z, 0x05040100u));
            const f16x4 Bif = mk4(__builtin_amdgcn_perm(q.y, q.x, 0x07060302u),
                                  __builtin_amdgcn_perm(q.w, q.z, 0x07060302u));
            const f32x4 Dr = MFMA16(Ar, Brf, MFMA16(An, Bif, cr4));
            const f32x4 Di = MFMA16(Ai, Brf, MFMA16(Ar, Bif, ci4));
            const int wg = wbase + (g << 4) + col;
            const int base_idx = h * NW + wg;
            #pragma unroll
            for (int j = 0; j < 4; ++j) {
                const int v = (ar << 2) + j;
                outp[v * (NH * NW) + base_idx] = make_float2(Dr[j], Di[j]);
            }
        }
    }
}

extern "C" void kernel_launch(void* const* d_in, const int* in_sizes, int n_in,
                              void* d_out, int out_size, void* d_ws, size_t ws_size,
                              hipStream_t stream) {
    const float* base     = (const float*)d_in[0];
    const float* mod_u    = (const float*)d_in[1];
    const float* mod_v    = (const float*)d_in[2];
    const float* del_u    = (const float*)d_in[3];
    const float* del_v    = (const float*)d_in[4];
    const float* exp_base = (const float*)d_in[5];
    const float* exp_mod  = (const float*)d_in[6];
    const float* exp_del  = (const float*)d_in[7];
    const float* bias_    = (const float*)d_in[8];
    const float* scale_   = (const float*)d_in[9];
    const float* coef     = (const float*)d_in[10];
    float* outp = (float*)d_out;

    const int blocks = (NH / 2) * (NW / 256);   // 2048
    const size_t mvT_floats = (size_t)NC * NW * NRM * 2;   // 1 MB
    const size_t dvT_floats = (size_t)NC * NW * NRD * 2;   // 0.5 MB
    const size_t need = (mvT_floats + dvT_floats) * sizeof(float);

    if (ws_size >= need) {
        float* mvT = (float*)d_ws;
        float* dvT = mvT + mvT_floats;
        transpose_v<<<(NC * NW) / 256, 256, 0, stream>>>(mod_v, del_v, mvT, dvT);
        fused_kernel<true><<<blocks, 256, 0, stream>>>(base, mod_u, mod_v, del_u, del_v,
                                                       exp_base, exp_mod, exp_del,
                                                       bias_, scale_, coef, outp, mvT, dvT);
    } else {
        fused_kernel<false><<<blocks, 256, 0, stream>>>(base, mod_u, mod_v, del_u, del_v,
                                                        exp_base, exp_mod, exp_del,
                                                        bias_, scale_, coef, outp,
                                                        (const float*)nullptr, (const float*)nullptr);
    }
}

// Round 7
// 89.415 us; speedup vs baseline: 1.2350x; 1.1090x over previous
//
#include <hip/hip_runtime.h>
#include <stdint.h>

#define NV 16
#define NC 16
#define NH 1024
#define NW 1024
#define NRM 8
#define NRD 4

typedef __attribute__((ext_vector_type(4))) _Float16 f16x4;
typedef __attribute__((ext_vector_type(2))) __fp16 fp16x2_raw;
typedef __attribute__((ext_vector_type(4))) float f32x4;
typedef __attribute__((ext_vector_type(2))) float f32x2;

#define MFMA16(a, b, c) __builtin_amdgcn_mfma_f32_16x16x16f16((a), (b), (c), 0, 0, 0)

__device__ __forceinline__ uint32_t pkh(float a, float b) {
    fp16x2_raw h = __builtin_amdgcn_cvt_pkrtz(a, b);   // lo = a, hi = b, RTZ
    return __builtin_bit_cast(uint32_t, h);
}

__device__ __forceinline__ f16x4 mk4(uint32_t lo, uint32_t hi) {
    union { uint32_t u[2]; f16x4 v; } t;
    t.u[0] = lo; t.u[1] = hi;
    return t.v;
}

// packed complex MAC: t(=tr,ti) += (a.x,a.y)*(b.x,b.y) complex, via 2x v_pk_fma_f32
__device__ __forceinline__ void cmac_pk(f32x2& t, f32x2 a, f32x2 b) {
    asm("v_pk_fma_f32 %0, %1, %2, %0 op_sel_hi:[0,1,1]"
        : "+v"(t) : "v"(a), "v"(b));
    asm("v_pk_fma_f32 %0, %1, %2, %0 op_sel:[1,1,0] op_sel_hi:[1,0,1] neg_lo:[1,0,0]"
        : "+v"(t) : "v"(a), "v"(b));
}

struct c2 { f32x2 a, b; };
__device__ __forceinline__ c2 split4(float4 v) {
    c2 r; r.a = f32x2{v.x, v.y}; r.b = f32x2{v.z, v.w}; return r;
}

// atan2 emitting REVOLUTIONS (atan2/2pi)
__device__ __forceinline__ float atan2_rev(float y, float x) {
    float ax = fabsf(x), ay = fabsf(y);
    float mx = fmaxf(ax, ay), mn = fminf(ax, ay);
    float a = mn * __builtin_amdgcn_rcpf(mx);
    float s = a * a;
    float p =              -0.00186549f;
    p = fmaf(p, s,  0.00838003f);
    p = fmaf(p, s, -0.01852970f);
    p = fmaf(p, s,  0.03080340f);
    p = fmaf(p, s, -0.05294381f);
    p = fmaf(p, s,  0.15915132f);
    p = p * a;
    float t = (ay > ax) ? (0.25f - p) : p;
    t = (x < 0.0f) ? (0.5f - t) : t;
    return (y < 0.0f) ? -t : t;
}

// exponent-domain constants: A=0.5*wr  B=wi*2pi*log2e  C=wr  D=wi*ln2/(4pi)
#define K_B 9.06472028f
#define K_D 0.05516054f

// -------- pre-pass: transpose mod_v/del_v to [c][w][r] (contiguous r) --------
__global__ __launch_bounds__(256)
void transpose_v(const float* __restrict__ mod_v, const float* __restrict__ del_v,
                 float* __restrict__ mvT, float* __restrict__ dvT)
{
    const int idx = blockIdx.x * 256 + threadIdx.x;   // c*NW + w
    const int c = idx >> 10, w = idx & 1023;
    float2* mt = reinterpret_cast<float2*>(mvT) + idx * NRM;
    const float2* ms = reinterpret_cast<const float2*>(mod_v) + c * NRM * NW + w;
    #pragma unroll
    for (int r = 0; r < NRM; ++r) mt[r] = ms[r * NW];
    float2* dt = reinterpret_cast<float2*>(dvT) + idx * NRD;
    const float2* dsrc = reinterpret_cast<const float2*>(del_v) + c * NRD * NW + w;
    #pragma unroll
    for (int r = 0; r < NRD; ++r) dt[r] = dsrc[r * NW];
}

struct V6 { f32x2 m0, m1, m2, m3, m4, m5, m6, m7, d0, d1, d2, d3; };

template <bool TR>
__device__ __forceinline__ V6 load_v(const float* __restrict__ mvT, const float* __restrict__ dvT,
                                     const float* __restrict__ mod_v, const float* __restrict__ del_v,
                                     int c, int w)
{
    V6 r;
    if (TR) {
        const float4* mp = reinterpret_cast<const float4*>(mvT) + (c * NW + w) * 4;
        c2 q0 = split4(mp[0]), q1 = split4(mp[1]), q2 = split4(mp[2]), q3 = split4(mp[3]);
        r.m0 = q0.a; r.m1 = q0.b; r.m2 = q1.a; r.m3 = q1.b;
        r.m4 = q2.a; r.m5 = q2.b; r.m6 = q3.a; r.m7 = q3.b;
        const float4* dp = reinterpret_cast<const float4*>(dvT) + (c * NW + w) * 2;
        c2 s0 = split4(dp[0]), s1 = split4(dp[1]);
        r.d0 = s0.a; r.d1 = s0.b; r.d2 = s1.a; r.d3 = s1.b;
    } else {
        const float2* m = reinterpret_cast<const float2*>(mod_v) + c * NRM * NW + w;
        float2 a0 = m[0], a1 = m[NW], a2 = m[2*NW], a3 = m[3*NW];
        float2 a4 = m[4*NW], a5 = m[5*NW], a6 = m[6*NW], a7 = m[7*NW];
        r.m0 = f32x2{a0.x, a0.y}; r.m1 = f32x2{a1.x, a1.y};
        r.m2 = f32x2{a2.x, a2.y}; r.m3 = f32x2{a3.x, a3.y};
        r.m4 = f32x2{a4.x, a4.y}; r.m5 = f32x2{a5.x, a5.y};
        r.m6 = f32x2{a6.x, a6.y}; r.m7 = f32x2{a7.x, a7.y};
        const float2* d = reinterpret_cast<const float2*>(del_v) + c * NRD * NW + w;
        float2 b0 = d[0], b1 = d[NW], b2 = d[2*NW], b3 = d[3*NW];
        r.d0 = f32x2{b0.x, b0.y}; r.d1 = f32x2{b1.x, b1.y};
        r.d2 = f32x2{b2.x, b2.y}; r.d3 = f32x2{b3.x, b3.y};
    }
    return r;
}

// lane l = (col = l&15, kb = l>>4): computes P[c = 4*kb+j][pixel col] for j=0..3,
// i.e. exactly its MFMA B-fragment. No LDS staging, no shuffle, no barrier-coupled
// transpose. Wave covers 16 pixels x 2 rows.
template <bool TR>
__global__ __launch_bounds__(256, 4)
void fused_kernel(const float* __restrict__ base, const float* __restrict__ mod_u,
                  const float* __restrict__ mod_v, const float* __restrict__ del_u,
                  const float* __restrict__ del_v, const float* __restrict__ exp_base,
                  const float* __restrict__ exp_mod, const float* __restrict__ exp_del,
                  const float* __restrict__ bias_, const float* __restrict__ scale_,
                  const float* __restrict__ coef, float* __restrict__ out,
                  const float* __restrict__ mvT, const float* __restrict__ dvT)
{
    __shared__ float4 uA4[NC][2][4];               // mod_u rows, 2 KB
    __shared__ float4 uD4[NC][2][2];               // del_u rows, 1 KB

    const int tid  = threadIdx.x;
    const int lane = tid & 63;
    const int wv   = tid >> 6;
    const int col  = lane & 15;
    const int kb   = lane >> 4;                    // c-block / v-block
    const int bw   = (int)(blockIdx.x & 15);       // 16 w-chunks of 64
    const int hp   = (int)(blockIdx.x >> 4);       // 512 row-pairs
    const int h0   = hp * 2;
    const int w    = (bw << 6) | (wv << 4) | col;  // this lane's pixel

    // ---------- cooperative preload of block-uniform u-tables ----------
    {
        float* uAf = reinterpret_cast<float*>(uA4);   // [c][rr][16 floats] = 512
        float* uDf = reinterpret_cast<float*>(uD4);   // [c][rr][8 floats]  = 256
        int i = tid;
        {
            const int c = i >> 5, rr = (i >> 4) & 1, e = i & 15;
            uAf[i] = mod_u[((c * NH) + (h0 + rr)) * (NRM * 2) + e];
        }
        i = tid + 256;
        {
            const int c = i >> 5, rr = (i >> 4) & 1, e = i & 15;
            uAf[i] = mod_u[((c * NH) + (h0 + rr)) * (NRM * 2) + e];
        }
        if (tid < 256) {
            const int c = tid >> 4, rr = (tid >> 3) & 1, e = tid & 7;
            uDf[tid] = del_u[((c * NH) + (h0 + rr)) * (NRD * 2) + e];
        }
    }
    __syncthreads();

    // ---------- per-lane A-fragments + bias-const accumulator seed ----------
    const int vv = col;                // M index (v) for A-frag
    const int c0 = kb << 2;            // K block (c)

    const float4 cfa = *reinterpret_cast<const float4*>(coef   + (vv * NC + c0) * 2);
    const float4 cfb = *reinterpret_cast<const float4*>(coef   + (vv * NC + c0) * 2 + 4);
    const float4 sca = *reinterpret_cast<const float4*>(scale_ + c0 * 2);
    const float4 scb = *reinterpret_cast<const float4*>(scale_ + c0 * 2 + 4);
    const float4 bia = *reinterpret_cast<const float4*>(bias_  + c0 * 2);
    const float4 bib = *reinterpret_cast<const float4*>(bias_  + c0 * 2 + 4);

    float c2r0 = cfa.x*sca.x - cfa.y*sca.y, c2i0 = cfa.x*sca.y + cfa.y*sca.x;
    float c2r1 = cfa.z*sca.z - cfa.w*sca.w, c2i1 = cfa.z*sca.w + cfa.w*sca.z;
    float c2r2 = cfb.x*scb.x - cfb.y*scb.y, c2i2 = cfb.x*scb.y + cfb.y*scb.x;
    float c2r3 = cfb.z*scb.z - cfb.w*scb.w, c2i3 = cfb.z*scb.w + cfb.w*scb.z;

    const f16x4 Ar = mk4(pkh(c2r0, c2r1), pkh(c2r2, c2r3));
    const f16x4 Ai = mk4(pkh(c2i0, c2i1), pkh(c2i2, c2i3));
    const f16x4 An = mk4(pkh(-c2i0, -c2i1), pkh(-c2i2, -c2i3));

    const f16x4 Kr = mk4(pkh(cfa.x, cfa.z), pkh(cfb.x, cfb.z));
    const f16x4 Ki = mk4(pkh(cfa.y, cfa.w), pkh(cfb.y, cfb.w));
    const f16x4 Kn = mk4(pkh(-cfa.y, -cfa.w), pkh(-cfb.y, -cfb.w));

    const f16x4 Bbr = mk4(pkh(bia.x, bia.z), pkh(bib.x, bib.z));
    const f16x4 Bbi = mk4(pkh(bia.y, bia.w), pkh(bib.y, bib.w));

    const f32x4 zero4 = {0.f, 0.f, 0.f, 0.f};
    const f32x4 cr4 = MFMA16(Kr, Bbr, MFMA16(Kn, Bbi, zero4));  // Re(sum coef*bias)
    const f32x4 ci4 = MFMA16(Ki, Bbr, MFMA16(Kr, Bbi, zero4));  // Im(sum coef*bias)

    // ---------- base contribution in exponent domain, per row ----------
    const float ebr = exp_base[0], ebi = exp_base[1];
    const float Ab = 0.5f * ebr, Bb = ebi * K_B, Cb = ebr, Db = ebi * K_D;
    float berr[2], beir[2];
    {
        const float2 b0 = reinterpret_cast<const float2*>(base)[(h0    ) * NW + w];
        const float2 b1 = reinterpret_cast<const float2*>(base)[(h0 + 1) * NW + w];
        const float L2b0 = __builtin_amdgcn_logf(fmaf(b0.x, b0.x, b0.y * b0.y));
        const float th0  = atan2_rev(b0.y, b0.x);
        const float L2b1 = __builtin_amdgcn_logf(fmaf(b1.x, b1.x, b1.y * b1.y));
        const float th1  = atan2_rev(b1.y, b1.x);
        berr[0] = fmaf(Ab, L2b0, -Bb * th0);
        beir[0] = fmaf(Cb, th0,   Db * L2b0);
        berr[1] = fmaf(Ab, L2b1, -Bb * th1);
        beir[1] = fmaf(Cb, th1,   Db * L2b1);
    }

    // ---------- main loop: this lane's 4 c-values = its B-fragment ----------
    float Pr[2][4], Pi[2][4];

    #pragma unroll
    for (int j = 0; j < 4; ++j) {
        const int c = c0 | j;
        const V6 cur = load_v<TR>(mvT, dvT, mod_v, del_v, c, w);

        const float2 em = reinterpret_cast<const float2*>(exp_mod)[c];
        const float2 ed = reinterpret_cast<const float2*>(exp_del)[c];
        const float kmA = 0.5f * em.x, kmB = em.y * K_B, kmC = em.x, kmD = em.y * K_D;
        const float kdA = 0.5f * ed.x, kdB = ed.y * K_B, kdC = ed.x, kdD = ed.y * K_D;

        #pragma unroll
        for (int rr = 0; rr < 2; ++rr) {
            const c2 ua  = split4(uA4[c][rr][0]);
            const c2 ub  = split4(uA4[c][rr][1]);
            const c2 uc_ = split4(uA4[c][rr][2]);
            const c2 ud  = split4(uA4[c][rr][3]);
            const c2 da  = split4(uD4[c][rr][0]);
            const c2 db  = split4(uD4[c][rr][1]);

            f32x2 tm = {0.f, 0.f};
            cmac_pk(tm, ua.a,  cur.m0); cmac_pk(tm, ua.b,  cur.m1);
            cmac_pk(tm, ub.a,  cur.m2); cmac_pk(tm, ub.b,  cur.m3);
            cmac_pk(tm, uc_.a, cur.m4); cmac_pk(tm, uc_.b, cur.m5);
            cmac_pk(tm, ud.a,  cur.m6); cmac_pk(tm, ud.b,  cur.m7);
            const float mr = tm[0], mi_ = tm[1];

            f32x2 td = {0.f, 0.f};
            cmac_pk(td, da.a, cur.d0); cmac_pk(td, da.b, cur.d1);
            cmac_pk(td, db.a, cur.d2); cmac_pk(td, db.b, cur.d3);
            const float dr = td[0], di = td[1];

            // mod power, base-folded: pb*pm = exp2(er2)·cis(2pi·eir)
            const float L2m = __builtin_amdgcn_logf(fmaf(mr, mr, mi_ * mi_));
            const float thm = atan2_rev(mi_, mr);
            const float er2 = fmaf(kmA, L2m, fmaf(-kmB, thm, berr[rr]));
            const float eir = fmaf(kmC, thm, fmaf(kmD, L2m, beir[rr]));
            const float mm  = __builtin_amdgcn_exp2f(er2);
            const float fm  = __builtin_amdgcn_fractf(eir);
            const float cv  = __builtin_amdgcn_cosf(fm);
            const float sv  = __builtin_amdgcn_sinf(fm);

            // del power
            const float L2d = __builtin_amdgcn_logf(fmaf(dr, dr, di * di));
            const float thd = atan2_rev(di, dr);
            const float er2d = fmaf(kdA, L2d, -kdB * thd);
            const float eird = fmaf(kdC, thd,  kdD * L2d);
            const float md  = __builtin_amdgcn_exp2f(er2d);
            const float fd  = __builtin_amdgcn_fractf(eird);
            const float cvd = __builtin_amdgcn_cosf(fd);
            const float svd = __builtin_amdgcn_sinf(fd);

            Pr[rr][j] = fmaf(mm, cv, md * cvd);
            Pi[rr][j] = fmaf(mm, sv, md * svd);
        }
    }

    // ---------- MFMA einsum straight from registers ----------
    float2* outp = reinterpret_cast<float2*>(out);
    #pragma unroll
    for (int rr = 0; rr < 2; ++rr) {
        const f16x4 Brf = mk4(pkh(Pr[rr][0], Pr[rr][1]), pkh(Pr[rr][2], Pr[rr][3]));
        const f16x4 Bif = mk4(pkh(Pi[rr][0], Pi[rr][1]), pkh(Pi[rr][2], Pi[rr][3]));
        const f32x4 Dr = MFMA16(Ar, Brf, MFMA16(An, Bif, cr4));
        const f32x4 Di = MFMA16(Ai, Brf, MFMA16(Ar, Bif, ci4));
        const int bidx = (h0 + rr) * NW + w;
        #pragma unroll
        for (int jj = 0; jj < 4; ++jj) {
            const int v = (kb << 2) + jj;
            outp[v * (NH * NW) + bidx] = make_float2(Dr[jj], Di[jj]);
        }
    }
}

extern "C" void kernel_launch(void* const* d_in, const int* in_sizes, int n_in,
                              void* d_out, int out_size, void* d_ws, size_t ws_size,
                              hipStream_t stream) {
    const float* base     = (const float*)d_in[0];
    const float* mod_u    = (const float*)d_in[1];
    const float* mod_v    = (const float*)d_in[2];
    const float* del_u    = (const float*)d_in[3];
    const float* del_v    = (const float*)d_in[4];
    const float* exp_base = (const float*)d_in[5];
    const float* exp_mod  = (const float*)d_in[6];
    const float* exp_del  = (const float*)d_in[7];
    const float* bias_    = (const float*)d_in[8];
    const float* scale_   = (const float*)d_in[9];
    const float* coef     = (const float*)d_in[10];
    float* outp = (float*)d_out;

    const int blocks = (NH / 2) * (NW / 64);   // 512 * 16 = 8192
    const size_t mvT_floats = (size_t)NC * NW * NRM * 2;   // 1 MB
    const size_t dvT_floats = (size_t)NC * NW * NRD * 2;   // 0.5 MB
    const size_t need = (mvT_floats + dvT_floats) * sizeof(float);

    if (ws_size >= need) {
        float* mvT = (float*)d_ws;
        float* dvT = mvT + mvT_floats;
        transpose_v<<<(NC * NW) / 256, 256, 0, stream>>>(mod_v, del_v, mvT, dvT);
        fused_kernel<true><<<blocks, 256, 0, stream>>>(base, mod_u, mod_v, del_u, del_v,
                                                       exp_base, exp_mod, exp_del,
                                                       bias_, scale_, coef, outp, mvT, dvT);
    } else {
        fused_kernel<false><<<blocks, 256, 0, stream>>>(base, mod_u, mod_v, del_u, del_v,
                                                        exp_base, exp_mod, exp_del,
                                                        bias_, scale_, coef, outp,
                                                        (const float*)nullptr, (const float*)nullptr);
    }
}